// Round 1
// baseline (570.277 us; speedup 1.0000x reference)
//
#include <hip/hip_runtime.h>
#include <stdint.h>

#define B_ 8
#define C_ 512
#define O_ 512
#define T_ 8192
#define KW 7
#define NW (O_*C_*KW)          // 1835008 weights
#define QT_ROWS (T_+32)        // per-batch rows in q_t: 4 zero rows front (0..3),
                               // data rows 4..8195, zero rows 8196..8199, tail pad
#define MT 128
#define NT 128
#define BK 32

typedef __attribute__((ext_vector_type(8))) short bf16x8;
typedef __attribute__((ext_vector_type(4))) float f32x4;

// async global->LDS, 16B per lane; LDS dest is wave-uniform base + lane*16
__device__ __forceinline__ void gld16(const void* g, void* l) {
  __builtin_amdgcn_global_load_lds(
      (const __attribute__((address_space(1))) unsigned int*)g,
      (__attribute__((address_space(3))) unsigned int*)l, 16, 0, 0);
}

// exact for small integers (|v| <= 256): low mantissa bits are zero
__device__ __forceinline__ unsigned short f2bf(float f) {
  return (unsigned short)(__builtin_bit_cast(unsigned int, f) >> 16);
}

// ---- K1: per-(b,t) RMS + global absmax of normalized tensor ----------------
__global__ __launch_bounds__(256) void k_rms(const float* __restrict__ x,
    const float* __restrict__ gamma, float* __restrict__ rms,
    unsigned* __restrict__ scale_bits)
{
  int g = blockIdx.x * 256 + threadIdx.x;   // one thread per (b,t)
  int b = g >> 13, t = g & (T_ - 1);
  const float* px = x + (size_t)b * C_ * T_ + t;
  float ss = 0.f, m = 0.f;
  #pragma unroll 8
  for (int c = 0; c < C_; ++c) {
    float v = px[(size_t)c * T_];           // lanes = consecutive t -> coalesced
    ss = fmaf(v, v, ss);
    m = fmaxf(m, fabsf(v * gamma[c]));
  }
  float r = 1.0f / sqrtf(ss * (1.0f / 512.0f) + 1e-6f);
  rms[g] = r;
  // block-reduce max via LDS atomic (candidates are non-negative -> uint order ok)
  __shared__ unsigned sm;
  if (threadIdx.x == 0) sm = 0u;
  __syncthreads();
  atomicMax(&sm, __float_as_uint(m * r));
  __syncthreads();
  if (threadIdx.x == 0) atomicMax(scale_bits, sm);
}

// ---- K2a: sum |w| -----------------------------------------------------------
__global__ __launch_bounds__(256) void k_wsum(const float* __restrict__ w,
                                              double* __restrict__ wsum)
{
  int tid = threadIdx.x;
  size_t g = (size_t)blockIdx.x * 256 + tid;
  float s = 0.f;
  for (size_t i = g; i < (size_t)NW; i += (size_t)gridDim.x * 256)
    s += fabsf(w[i]);
  __shared__ float red[256];
  red[tid] = s; __syncthreads();
  for (int h = 128; h > 0; h >>= 1) {
    if (tid < h) red[tid] += red[tid + h];
    __syncthreads();
  }
  if (tid == 0) atomicAdd(wsum, (double)red[0]);
}

// ---- K2b: ternary-quantize weights into wq[k][o][c] (bf16 {-1,0,1}) --------
__global__ __launch_bounds__(256) void k_wq(const float* __restrict__ w,
    const double* __restrict__ wsum, unsigned short* __restrict__ wq)
{
  int g = blockIdx.x * 256 + threadIdx.x;   // g = (kk*O_ + o)*C_ + c
  int kk  = g >> 18;                        // /(O_*C_) = /262144
  int rem = g & (O_*C_ - 1);
  int o = rem >> 9, c = rem & (C_ - 1);
  float wsc = fmaxf((float)(*wsum * (1.0 / (double)NW)), 1e-4f);
  float v = w[((size_t)o * C_ + c) * KW + kk];
  float q = rintf(fminf(fmaxf(v / wsc, -1.f), 1.f));
  wq[g] = f2bf(q);
}

// ---- K2c: zero the t-halo rows of q_t --------------------------------------
__global__ void k_halo(unsigned short* __restrict__ qt) {
  int g = blockIdx.x * 256 + threadIdx.x;   // 8 b * 8 rows * 512 c = 32768
  int b = g >> 12, rr = (g >> 9) & 7, c = g & 511;
  int row = (rr < 4) ? rr : (T_ + rr);      // rows 0..3 and 8196..8199
  qt[((size_t)b * QT_ROWS + row) * C_ + c] = 0;
}

// ---- K3: quantize activations + transpose to q_t[b][t+4][c] (bf16) ---------
__global__ __launch_bounds__(256) void k_quant(const float* __restrict__ x,
    const float* __restrict__ gamma, const float* __restrict__ rms,
    const unsigned* __restrict__ scale_bits, unsigned short* __restrict__ qt)
{
  __shared__ float tile[64][65];            // +1 pad: conflict-free transpose
  int tt0 = blockIdx.x * 64;
  int c0  = blockIdx.y * 64;
  int b   = blockIdx.z;
  int tl = threadIdx.x & 63;
  int q4 = threadIdx.x >> 6;
  float qmul = 127.0f / fmaxf(__uint_as_float(*scale_bits), 1e-5f);
  const float* px = x + ((size_t)b * C_ + c0) * T_ + tt0;
  float rr = rms[b * T_ + tt0 + tl];
  #pragma unroll
  for (int cc = q4; cc < 64; cc += 4) {     // read coalesced along t
    float v = px[(size_t)cc * T_ + tl];
    float xn = (v * rr) * gamma[c0 + cc];
    tile[cc][tl] = rintf(fminf(fmaxf(xn * qmul, -128.f), 127.f));
  }
  __syncthreads();
  unsigned short* pq = qt + ((size_t)b * QT_ROWS + (tt0 + 4)) * C_ + c0;
  #pragma unroll
  for (int t2 = q4; t2 < 64; t2 += 4) {     // write coalesced along c
    pq[(size_t)t2 * C_ + tl] = f2bf(tile[tl][t2]);
  }
}

// ---- K4: conv as MFMA GEMM: out[b][o][t] = alpha * sum_{k,c} Wk[o,c]*q[c,t+k-3]
__global__ __launch_bounds__(256) void k_conv(
    const unsigned short* __restrict__ wq,   // [KW][O_][C_] bf16
    const unsigned short* __restrict__ qt,   // [B_][QT_ROWS][C_] bf16 (row = t+4)
    float* __restrict__ out,
    const unsigned* __restrict__ scale_bits,
    const double* __restrict__ wsum)
{
  __shared__ __attribute__((aligned(16))) unsigned short lA[MT * BK];   // 8 KB
  __shared__ __attribute__((aligned(16))) unsigned short lB[144 * BK];  // 9 KB
  int tid = threadIdx.x;
  int wave = tid >> 6, lane = tid & 63;
  int quad = lane >> 4, l16 = lane & 15;
  int lrow = lane >> 2, lch = lane & 3;     // staging: 16 rows x 4 chunks / instr
  int t0 = blockIdx.x * NT;
  int o0 = blockIdx.y * MT;
  int b  = blockIdx.z;
  int wm = wave & 1, wn = wave >> 1;        // 2x2 wave grid, 64x64 out per wave

  const unsigned short* qt_b = qt + (size_t)b * QT_ROWS * C_;

  f32x4 acc[4][4] = {};

  for (int c0 = 0; c0 < C_; c0 += BK) {
    // stage B: 144 t-rows (t = t0-8+r), 32 c each; reused for all 7 taps.
    // 9 wave-instrs total (wave0: i=0,4,8; others 2 each), all lanes full.
    for (int i = wave; i < 9; i += 4) {
      const unsigned short* gB = qt_b
          + (long long)(t0 - 4 + i * 16 + lrow) * C_ + (c0 + lch * 8);
      gld16(gB, &lB[i * 512 + lane * 8]);
    }
    for (int k = 0; k < KW; ++k) {
      // stage A: Wk[o0..o0+127][c0..c0+31], 8 wave-instrs (2 per wave)
      for (int i = wave; i < 8; i += 4) {
        const unsigned short* gA = wq
            + ((size_t)(k * O_ + o0 + i * 16 + lrow)) * C_ + (c0 + lch * 8);
        gld16(gA, &lA[i * 512 + lane * 8]);
      }
      __syncthreads();
      bf16x8 af[4], bf[4];
      #pragma unroll
      for (int mt = 0; mt < 4; ++mt)        // A[m=lane&15][k=quad*8+j]
        af[mt] = *(const bf16x8*)&lA[(wm * 64 + mt * 16 + l16) * BK + quad * 8];
      int sft = k - 3 + 8;                  // tap shift as LDS row offset
      #pragma unroll
      for (int nt = 0; nt < 4; ++nt)        // B^T[t][c]: 8 contiguous c per lane
        bf[nt] = *(const bf16x8*)&lB[(wn * 64 + nt * 16 + l16 + sft) * BK + quad * 8];
      #pragma unroll
      for (int mt = 0; mt < 4; ++mt)
        #pragma unroll
        for (int nt = 0; nt < 4; ++nt)
          acc[mt][nt] = __builtin_amdgcn_mfma_f32_16x16x32_bf16(
              af[mt], bf[nt], acc[mt][nt], 0, 0, 0);
      __syncthreads();
    }
  }
  // epilogue: dequant scale. C/D layout: col=lane&15, row=quad*4+reg
  float sc  = fmaxf(__uint_as_float(*scale_bits), 1e-5f);
  float wsc = fmaxf((float)(*wsum * (1.0 / (double)NW)), 1e-4f);
  float alpha = sc * (1.0f / 127.0f) * wsc;
  #pragma unroll
  for (int mt = 0; mt < 4; ++mt) {
    int o = o0 + wm * 64 + mt * 16 + quad * 4;
    #pragma unroll
    for (int nt = 0; nt < 4; ++nt) {
      int t = t0 + wn * 64 + nt * 16 + l16;
      float* po = out + ((size_t)b * O_ + o) * T_ + t;
      #pragma unroll
      for (int r2 = 0; r2 < 4; ++r2)
        po[(size_t)r2 * T_] = acc[mt][nt][r2] * alpha;
    }
  }
}

extern "C" void kernel_launch(void* const* d_in, const int* in_sizes, int n_in,
                              void* d_out, int out_size, void* d_ws, size_t ws_size,
                              hipStream_t stream)
{
  const float* x     = (const float*)d_in[0];
  const float* w     = (const float*)d_in[1];
  const float* gamma = (const float*)d_in[2];
  float* out = (float*)d_out;
  char* ws = (char*)d_ws;
  // ws layout:
  //   [0]       unsigned scale_bits (absmax of normalized x, as float bits)
  //   [16]      double   wsum (sum |w|)
  //   [256]     float    rms[B_*T_]                       (256 KB)
  //   [262400]  bf16     wq[KW][O_][C_]                   (3.67 MB)
  //   [3932416] bf16     q_t[B_][QT_ROWS][C_]             (67.4 MB)
  unsigned* scale_bits = (unsigned*)ws;
  double*   wsum       = (double*)(ws + 16);
  float*    rms        = (float*)(ws + 256);
  unsigned short* wq   = (unsigned short*)(ws + 262400);
  unsigned short* qt   = (unsigned short*)(ws + 3932416);

  hipMemsetAsync(ws, 0, 256, stream);
  k_rms  <<<dim3(B_*T_/256),        256, 0, stream>>>(x, gamma, rms, scale_bits);
  k_wsum <<<dim3(1792),             256, 0, stream>>>(w, wsum);
  k_wq   <<<dim3(NW/256),           256, 0, stream>>>(w, wsum, wq);
  k_halo <<<dim3(128),              256, 0, stream>>>(qt);
  k_quant<<<dim3(T_/64, C_/64, B_), 256, 0, stream>>>(x, gamma, rms, scale_bits, qt);
  k_conv <<<dim3(T_/NT, O_/MT, B_), 256, 0, stream>>>(wq, qt, out, scale_bits, wsum);
}

// Round 2
// 445.131 us; speedup vs baseline: 1.2811x; 1.2811x over previous
//
#include <hip/hip_runtime.h>
#include <stdint.h>

#define B_ 8
#define C_ 512
#define O_ 512
#define T_ 8192
#define KW 7
#define NW (O_*C_*KW)          // 1835008 weights
#define QT_ROWS (T_+32)        // qt row j holds t = j-4; rows 0..3 and 8196..8199 zeroed
#define MT 64
#define NT 256
#define BK 32
#define BROWS 272              // staged B rows per tile (256 + halo, 17x16)

typedef __attribute__((ext_vector_type(8))) short bf16x8;
typedef __attribute__((ext_vector_type(4))) float f32x4;

// async global->LDS, 16B per lane; LDS dest is wave-uniform base + lane*16
__device__ __forceinline__ void gld16(const void* g, void* l) {
  __builtin_amdgcn_global_load_lds(
      (const __attribute__((address_space(1))) unsigned int*)g,
      (__attribute__((address_space(3))) unsigned int*)l, 16, 0, 0);
}

// exact for small integers (|v| <= 256): low mantissa bits are zero
__device__ __forceinline__ unsigned short f2bf(float f) {
  return (unsigned short)(__builtin_bit_cast(unsigned int, f) >> 16);
}

// ---- K1: per-(b,t) RMS + global absmax of normalized tensor ----------------
// c-split x4: block = 64 t x 512 c, 1024 blocks -> 16 waves/CU (was 1 block/CU)
__global__ __launch_bounds__(256) void k_rms(const float* __restrict__ x,
    const float* __restrict__ gamma, float* __restrict__ rms,
    unsigned* __restrict__ scale_bits)
{
  int tid = threadIdx.x, tl = tid & 63, cq = tid >> 6;
  int bt = blockIdx.x * 64 + tl;            // linear (b,t); 64 | 8192 so no b-cross
  int b = bt >> 13, t = bt & (T_ - 1);
  const float* px = x + ((size_t)b * C_ + cq * 128) * T_ + t;
  const float* pg = gamma + cq * 128;       // wave-uniform index -> scalar loads
  float ss = 0.f, m = 0.f;
  #pragma unroll 8
  for (int cc = 0; cc < 128; ++cc) {
    float v = px[(size_t)cc * T_];          // lanes = consecutive t -> coalesced
    ss = fmaf(v, v, ss);
    m = fmaxf(m, fabsf(v * pg[cc]));
  }
  __shared__ float s_ss[4][64];
  __shared__ float s_m[4][64];
  __shared__ unsigned sm;
  s_ss[cq][tl] = ss; s_m[cq][tl] = m;
  if (tid == 0) sm = 0u;
  __syncthreads();
  if (cq == 0) {
    float tot = s_ss[0][tl] + s_ss[1][tl] + s_ss[2][tl] + s_ss[3][tl];
    float r = 1.0f / sqrtf(tot * (1.0f / 512.0f) + 1e-6f);
    rms[bt] = r;
    float mm = fmaxf(fmaxf(s_m[0][tl], s_m[1][tl]),
                     fmaxf(s_m[2][tl], s_m[3][tl])) * r;
    atomicMax(&sm, __float_as_uint(mm));    // candidates >=0 -> uint order ok
  }
  __syncthreads();
  if (tid == 0) atomicMax(scale_bits, sm);
}

// ---- K2a: sum |w| (+ fused qt halo zeroing in first 128 blocks) ------------
__global__ __launch_bounds__(256) void k_wsum(const float* __restrict__ w,
    double* __restrict__ wsum, unsigned short* __restrict__ qt)
{
  int tid = threadIdx.x;
  if (blockIdx.x < 128) {                   // zero t-halo rows of q_t
    int g = blockIdx.x * 256 + tid;         // 8 b * 8 rows * 512 c = 32768
    int b = g >> 12, rr = (g >> 9) & 7, c = g & 511;
    int row = (rr < 4) ? rr : (T_ + rr);    // rows 0..3 and 8196..8199
    qt[((size_t)b * QT_ROWS + row) * C_ + c] = 0;
  }
  size_t g = (size_t)blockIdx.x * 256 + tid;
  float s = 0.f;
  for (size_t i = g; i < (size_t)NW; i += (size_t)gridDim.x * 256)
    s += fabsf(w[i]);
  __shared__ float red[256];
  red[tid] = s; __syncthreads();
  for (int h = 128; h > 0; h >>= 1) {
    if (tid < h) red[tid] += red[tid + h];
    __syncthreads();
  }
  if (tid == 0) atomicAdd(wsum, (double)red[0]);
}

// ---- K2b: ternary-quantize weights into wq[k][o][c] (bf16 {-1,0,1}) --------
// thread g=(o,c) reads its 7 contiguous taps, writes 7 coalesced planes
__global__ __launch_bounds__(256) void k_wq(const float* __restrict__ w,
    const double* __restrict__ wsum, unsigned short* __restrict__ wq)
{
  int g = blockIdx.x * 256 + threadIdx.x;   // g = o*C_ + c
  float wsc = fmaxf((float)(*wsum * (1.0 / (double)NW)), 1e-4f);
  const float* pw = w + (size_t)g * KW;
  #pragma unroll
  for (int kk = 0; kk < KW; ++kk) {
    float q = rintf(fminf(fmaxf(pw[kk] / wsc, -1.f), 1.f));
    wq[(size_t)kk * (O_ * C_) + g] = f2bf(q);
  }
}

// ---- K3: quantize activations + transpose to q_t[b][t+4][c] (bf16) ---------
__global__ __launch_bounds__(256) void k_quant(const float* __restrict__ x,
    const float* __restrict__ gamma, const float* __restrict__ rms,
    const unsigned* __restrict__ scale_bits, unsigned short* __restrict__ qt)
{
  __shared__ float tile[64][65];            // +1 pad: conflict-free transpose
  int tid = threadIdx.x;
  int tt0 = blockIdx.x * 64;
  int c0  = blockIdx.y * 64;
  int b   = blockIdx.z;
  int tl = tid & 63;
  int q4 = tid >> 6;
  float qmul = 127.0f / fmaxf(__uint_as_float(*scale_bits), 1e-5f);
  const float* px = x + ((size_t)b * C_ + c0) * T_ + tt0;
  float rr = rms[b * T_ + tt0 + tl];
  #pragma unroll
  for (int cc = q4; cc < 64; cc += 4) {     // read coalesced along t
    float v = px[(size_t)cc * T_ + tl];
    float xn = (v * rr) * gamma[c0 + cc];
    tile[cc][tl] = rintf(fminf(fmaxf(xn * qmul, -128.f), 127.f));
  }
  __syncthreads();
  // write 8B/lane: thread handles 4 consecutive c for 4 t rows
  int c4 = (tid & 15) * 4, tb = tid >> 4;
  unsigned short* pq = qt + ((size_t)b * QT_ROWS + (tt0 + 4)) * C_ + c0;
  #pragma unroll
  for (int it = 0; it < 4; ++it) {
    int t2 = tb + it * 16;
    unsigned long long v =
          (unsigned long long)f2bf(tile[c4 + 0][t2])
        | ((unsigned long long)f2bf(tile[c4 + 1][t2]) << 16)
        | ((unsigned long long)f2bf(tile[c4 + 2][t2]) << 32)
        | ((unsigned long long)f2bf(tile[c4 + 3][t2]) << 48);
    *(unsigned long long*)&pq[(size_t)t2 * C_ + c4] = v;
  }
}

// ---- K4: conv as MFMA GEMM: out[b][o][t] = alpha * sum_{k,c} Wk[o,c]*q[c,t+k-3]
// MT=64 x NT=256 tile; all 7 taps of A staged at once (112 MFMA between barriers).
// LDS chunk position XOR-swizzled by (row>>1)&3 -> 2-way (free) bank access.
__global__ __launch_bounds__(256, 3) void k_conv(
    const unsigned short* __restrict__ wq,   // [KW][O_][C_] bf16
    const unsigned short* __restrict__ qt,   // [B_][QT_ROWS][C_] bf16 (row = t+4)
    float* __restrict__ out,
    const unsigned* __restrict__ scale_bits,
    const double* __restrict__ wsum)
{
  __shared__ __attribute__((aligned(16))) unsigned short lA[KW * 64 * BK]; // 28 KB
  __shared__ __attribute__((aligned(16))) unsigned short lB[BROWS * BK];   // 17 KB
  int tid = threadIdx.x;
  int wave = tid >> 6, lane = tid & 63;
  int quad = lane >> 4, l16 = lane & 15;
  int lrow = lane >> 2;                      // staging: 16 rows x 4 chunks / instr
  int dch = ((lane & 3) - (lane >> 3)) & 3;  // swizzled data chunk for this lane
  int t0 = blockIdx.x * NT;
  int o0 = blockIdx.y * MT;
  int b  = blockIdx.z;

  const unsigned short* qt_b = qt + (size_t)b * QT_ROWS * C_;

  f32x4 acc[4][4] = {};

  for (int c0 = 0; c0 < C_; c0 += BK) {
    // stage B: qt rows t0..t0+271 (t = t0-4 .. t0+267), 32 c, 17 wave-instrs
    for (int i = wave; i < 17; i += 4) {
      const unsigned short* gB =
          qt_b + (size_t)(t0 + i * 16 + lrow) * C_ + (c0 + dch * 8);
      gld16(gB, &lB[i * 512 + lane * 8]);
    }
    // stage A: all 7 taps, 64 o-rows x 32 c each, 28 wave-instrs
    for (int i = wave; i < 28; i += 4) {
      int k = i >> 2, ii = i & 3;
      const unsigned short* gA =
          wq + (size_t)(k * O_ + o0 + ii * 16 + lrow) * C_ + (c0 + dch * 8);
      gld16(gA, &lA[i * 512 + lane * 8]);
    }
    __syncthreads();
    #pragma unroll
    for (int k = 0; k < KW; ++k) {
      bf16x8 af[4], bf[4];
      #pragma unroll
      for (int mt = 0; mt < 4; ++mt) {      // A[m=lane&15][k=quad*8+j]
        int r = mt * 16 + l16;
        af[mt] = *(const bf16x8*)
            &lA[k * 2048 + r * BK + (((quad + (r >> 1)) & 3) * 8)];
      }
      int sft = k + 1;                       // tap shift as LDS row offset
      #pragma unroll
      for (int nt = 0; nt < 4; ++nt) {      // B^T[t][c]: 8 contiguous c per lane
        int r = wave * 64 + nt * 16 + l16 + sft;
        bf[nt] = *(const bf16x8*)
            &lB[r * BK + (((quad + (r >> 1)) & 3) * 8)];
      }
      #pragma unroll
      for (int mt = 0; mt < 4; ++mt)
        #pragma unroll
        for (int nt = 0; nt < 4; ++nt)
          acc[mt][nt] = __builtin_amdgcn_mfma_f32_16x16x32_bf16(
              af[mt], bf[nt], acc[mt][nt], 0, 0, 0);
    }
    __syncthreads();
  }
  // epilogue: dequant scale. C/D layout: col=lane&15, row=quad*4+reg
  float sc  = fmaxf(__uint_as_float(*scale_bits), 1e-5f);
  float wsc = fmaxf((float)(*wsum * (1.0 / (double)NW)), 1e-4f);
  float alpha = sc * (1.0f / 127.0f) * wsc;
  #pragma unroll
  for (int mt = 0; mt < 4; ++mt) {
    int o = o0 + mt * 16 + quad * 4;
    #pragma unroll
    for (int nt = 0; nt < 4; ++nt) {
      int t = t0 + wave * 64 + nt * 16 + l16;
      float* po = out + ((size_t)b * O_ + o) * T_ + t;
      #pragma unroll
      for (int r2 = 0; r2 < 4; ++r2)
        po[(size_t)r2 * T_] = acc[mt][nt][r2] * alpha;
    }
  }
}

extern "C" void kernel_launch(void* const* d_in, const int* in_sizes, int n_in,
                              void* d_out, int out_size, void* d_ws, size_t ws_size,
                              hipStream_t stream)
{
  const float* x     = (const float*)d_in[0];
  const float* w     = (const float*)d_in[1];
  const float* gamma = (const float*)d_in[2];
  float* out = (float*)d_out;
  char* ws = (char*)d_ws;
  // ws layout:
  //   [0]       unsigned scale_bits (absmax of normalized x, as float bits)
  //   [16]      double   wsum (sum |w|)
  //   [256]     float    rms[B_*T_]                       (256 KB)
  //   [262400]  bf16     wq[KW][O_][C_]                   (3.67 MB)
  //   [3932416] bf16     q_t[B_][QT_ROWS][C_]             (67.4 MB)
  unsigned* scale_bits = (unsigned*)ws;
  double*   wsum       = (double*)(ws + 16);
  float*    rms        = (float*)(ws + 256);
  unsigned short* wq   = (unsigned short*)(ws + 262400);
  unsigned short* qt   = (unsigned short*)(ws + 3932416);

  hipMemsetAsync(ws, 0, 256, stream);
  k_rms  <<<dim3(B_*T_/64),         256, 0, stream>>>(x, gamma, rms, scale_bits);
  k_wsum <<<dim3(1792),             256, 0, stream>>>(w, wsum, qt);
  k_wq   <<<dim3(O_*C_/256),        256, 0, stream>>>(w, wsum, wq);
  k_quant<<<dim3(T_/64, C_/64, B_), 256, 0, stream>>>(x, gamma, rms, scale_bits, qt);
  k_conv <<<dim3(T_/NT, O_/MT, B_), 256, 0, stream>>>(wq, qt, out, scale_bits, wsum);
}

// Round 3
// 370.444 us; speedup vs baseline: 1.5394x; 1.2016x over previous
//
#include <hip/hip_runtime.h>
#include <stdint.h>

#define B_ 8
#define C_ 512
#define O_ 512
#define T_ 8192
#define KW 7
#define NW (O_*C_*KW)          // 1835008 weights
#define QT_ROWS (T_+32)        // qa row j holds t = j-4; rows 0..3 and 8196..8199 zeroed
#define MT 64
#define NT 256
#define BK 64                  // i8 channels per K-tile (64 B rows)
#define BROWS 272              // staged B rows per tile (256 + halo)

typedef __attribute__((ext_vector_type(4))) int i32x4;

// async global->LDS, 16B per lane; LDS dest is wave-uniform base + lane*16
__device__ __forceinline__ void gld16(const void* g, void* l) {
  __builtin_amdgcn_global_load_lds(
      (const __attribute__((address_space(1))) unsigned int*)g,
      (__attribute__((address_space(3))) unsigned int*)l, 16, 0, 0);
}

// ---- K1: per-(b,t) RMS + global absmax of normalized tensor ----------------
// block = 256 t x 512 c (c-split x4 over waves); float4 reads (16 B/lane)
__global__ __launch_bounds__(256) void k_rms(const float* __restrict__ x,
    const float* __restrict__ gamma, float* __restrict__ rms,
    unsigned* __restrict__ scale_bits)
{
  int tid = threadIdx.x, tl = tid & 63, cq = tid >> 6;
  int bt0 = blockIdx.x * 256;               // 256 | 8192 so no b-cross
  int b = bt0 >> 13, t = (bt0 & (T_ - 1)) + tl * 4;
  const float4* px = (const float4*)(x + ((size_t)b * C_ + cq * 128) * T_ + t);
  const float* pg = gamma + cq * 128;       // wave-uniform index -> scalar loads
  float4 ss = {0.f, 0.f, 0.f, 0.f};
  float4 mx = {0.f, 0.f, 0.f, 0.f};
  #pragma unroll 8
  for (int cc = 0; cc < 128; ++cc) {
    float4 v = px[(size_t)cc * (T_ / 4)];   // lanes consecutive -> 1 KB/wave-load
    float g = pg[cc];
    ss.x = fmaf(v.x, v.x, ss.x); ss.y = fmaf(v.y, v.y, ss.y);
    ss.z = fmaf(v.z, v.z, ss.z); ss.w = fmaf(v.w, v.w, ss.w);
    mx.x = fmaxf(mx.x, fabsf(v.x * g)); mx.y = fmaxf(mx.y, fabsf(v.y * g));
    mx.z = fmaxf(mx.z, fabsf(v.z * g)); mx.w = fmaxf(mx.w, fabsf(v.w * g));
  }
  __shared__ float4 s_ss[4][64];
  __shared__ float4 s_m[4][64];
  __shared__ unsigned sm;
  s_ss[cq][tl] = ss; s_m[cq][tl] = mx;
  if (tid == 0) sm = 0u;
  __syncthreads();
  if (cq == 0) {
    float4 a = s_ss[0][tl], b4 = s_ss[1][tl], c4 = s_ss[2][tl], d4 = s_ss[3][tl];
    float4 r;
    r.x = 1.0f / sqrtf((a.x + b4.x + c4.x + d4.x) * (1.0f / 512.0f) + 1e-6f);
    r.y = 1.0f / sqrtf((a.y + b4.y + c4.y + d4.y) * (1.0f / 512.0f) + 1e-6f);
    r.z = 1.0f / sqrtf((a.z + b4.z + c4.z + d4.z) * (1.0f / 512.0f) + 1e-6f);
    r.w = 1.0f / sqrtf((a.w + b4.w + c4.w + d4.w) * (1.0f / 512.0f) + 1e-6f);
    ((float4*)rms)[blockIdx.x * 64 + tl] = r;
    float4 m0 = s_m[0][tl], m1 = s_m[1][tl], m2 = s_m[2][tl], m3 = s_m[3][tl];
    float mm = fmaxf(fmaxf(fmaxf(m0.x, m1.x), fmaxf(m2.x, m3.x)) * r.x,
              fmaxf(fmaxf(fmaxf(m0.y, m1.y), fmaxf(m2.y, m3.y)) * r.y,
              fmaxf(fmaxf(fmaxf(m0.z, m1.z), fmaxf(m2.z, m3.z)) * r.z,
                    fmaxf(fmaxf(m0.w, m1.w), fmaxf(m2.w, m3.w)) * r.w)));
    atomicMax(&sm, __float_as_uint(mm));    // candidates >=0 -> uint order ok
  }
  __syncthreads();
  if (tid == 0) atomicMax(scale_bits, sm);
}

// ---- K2a: sum |w| (+ fused qa halo zeroing in first 32 blocks) -------------
__global__ __launch_bounds__(256) void k_wsum(const float* __restrict__ w,
    double* __restrict__ wsum, char* __restrict__ qa)
{
  int tid = threadIdx.x;
  if (blockIdx.x < 32) {                    // zero t-halo rows of qa (4 B writes)
    int g4 = blockIdx.x * 256 + tid;        // 0..8191 -> 32 KB
    int b = g4 >> 10;
    int idx = (g4 & 1023) * 4;              // byte idx within b's 8 halo rows
    int rr = idx >> 9, c = idx & 511;
    int row = (rr < 4) ? rr : (T_ + rr);    // rows 0..3 and 8196..8199
    *(unsigned*)&qa[((size_t)b * QT_ROWS + row) * C_ + c] = 0u;
  }
  size_t g = (size_t)blockIdx.x * 256 + tid;
  float s = 0.f;
  for (size_t i = g; i < (size_t)NW; i += (size_t)gridDim.x * 256)
    s += fabsf(w[i]);
  __shared__ float red[256];
  red[tid] = s; __syncthreads();
  for (int h = 128; h > 0; h >>= 1) {
    if (tid < h) red[tid] += red[tid + h];
    __syncthreads();
  }
  if (tid == 0) atomicAdd(wsum, (double)red[0]);
}

// ---- K2b: ternary-quantize weights into wqi[k][o][c] (int8 {-1,0,1}) -------
__global__ __launch_bounds__(256) void k_wq(const float* __restrict__ w,
    const double* __restrict__ wsum, char* __restrict__ wqi)
{
  int g = blockIdx.x * 256 + threadIdx.x;   // g = o*C_ + c
  float wsc = fmaxf((float)(*wsum * (1.0 / (double)NW)), 1e-4f);
  const float* pw = w + (size_t)g * KW;
  #pragma unroll
  for (int kk = 0; kk < KW; ++kk) {
    float q = rintf(fminf(fmaxf(pw[kk] / wsc, -1.f), 1.f));
    wqi[(size_t)kk * (O_ * C_) + g] = (char)(int)q;
  }
}

// ---- K3: quantize activations + transpose to qa[b][t+4][c] (int8) ----------
__global__ __launch_bounds__(256) void k_quant(const float* __restrict__ x,
    const float* __restrict__ gamma, const float* __restrict__ rms,
    const unsigned* __restrict__ scale_bits, char* __restrict__ qa)
{
  __shared__ float tile[64][65];            // +1 pad: conflict-free transpose
  int tid = threadIdx.x;
  int tt0 = blockIdx.x * 64;
  int c0  = blockIdx.y * 64;
  int b   = blockIdx.z;
  int tl = tid & 63;
  int q4 = tid >> 6;
  float qmul = 127.0f / fmaxf(__uint_as_float(*scale_bits), 1e-5f);
  const float* px = x + ((size_t)b * C_ + c0) * T_ + tt0;
  float rr = rms[b * T_ + tt0 + tl];
  #pragma unroll
  for (int cc = q4; cc < 64; cc += 4) {     // read coalesced along t
    float v = px[(size_t)cc * T_ + tl];
    float xn = (v * rr) * gamma[c0 + cc];
    tile[cc][tl] = rintf(fminf(fmaxf(xn * qmul, -128.f), 127.f));
  }
  __syncthreads();
  // pack 4 consecutive c into a dword; 4 t-rows per thread
  int c4 = (tid & 15) * 4, tb = tid >> 4;
  char* pq = qa + ((size_t)b * QT_ROWS + (tt0 + 4)) * C_ + c0;
  #pragma unroll
  for (int it = 0; it < 4; ++it) {
    int t2 = tb + it * 16;
    unsigned u = ((unsigned)(unsigned char)(char)(int)tile[c4 + 0][t2])
               | ((unsigned)(unsigned char)(char)(int)tile[c4 + 1][t2] << 8)
               | ((unsigned)(unsigned char)(char)(int)tile[c4 + 2][t2] << 16)
               | ((unsigned)(unsigned char)(char)(int)tile[c4 + 3][t2] << 24);
    *(unsigned*)&pq[(size_t)t2 * C_ + c4] = u;
  }
}

// ---- K4: conv as i8 MFMA GEMM (exact): out = alpha * sum_{k,c} Wk[o,c]*q[c,t+k-3]
// MT=64 x NT=256; all 7 taps staged; K=64 per MFMA; swizzled LDS (0 conflicts).
__global__ __launch_bounds__(256, 3) void k_conv(
    const char* __restrict__ wqi,            // [KW][O_][C_] int8
    const char* __restrict__ qa,             // [B_][QT_ROWS][C_] int8 (row = t+4)
    float* __restrict__ out,
    const unsigned* __restrict__ scale_bits,
    const double* __restrict__ wsum)
{
  __shared__ __attribute__((aligned(16))) char lA[KW * 64 * BK];  // 28 KB
  __shared__ __attribute__((aligned(16))) char lB[BROWS * BK];    // 17 KB
  int tid = threadIdx.x;
  int wave = tid >> 6, lane = tid & 63;
  int quad = lane >> 4, l16 = lane & 15;
  int lrow = lane >> 2;                      // staging: 16 rows x 4 chunks / instr
  int dch = ((lane & 3) - (lane >> 3)) & 3;  // swizzled data chunk for this lane
  int t0 = blockIdx.x * NT;
  int o0 = blockIdx.y * MT;
  int b  = blockIdx.z;

  const char* qa_b = qa + (size_t)b * QT_ROWS * C_;

  i32x4 acc[4][4] = {};

  for (int c0 = 0; c0 < C_; c0 += BK) {
    // stage B: qa rows t0..t0+271 (t = t0-4 .. t0+267), 64 c; 17 instrs
    for (int i = wave; i < 17; i += 4) {
      const char* gB = qa_b + (size_t)(t0 + i * 16 + lrow) * C_ + (c0 + dch * 16);
      gld16(gB, &lB[i * 1024 + lane * 16]);
    }
    // stage A: all 7 taps, 64 o-rows x 64 c each; 28 instrs
    for (int i = wave; i < 28; i += 4) {
      int k = i >> 2, ii = i & 3;
      const char* gA =
          wqi + (size_t)(k * O_ + o0 + ii * 16 + lrow) * C_ + (c0 + dch * 16);
      gld16(gA, &lA[i * 1024 + lane * 16]);
    }
    __syncthreads();
    #pragma unroll
    for (int k = 0; k < KW; ++k) {
      i32x4 af[4], bf[4];
      #pragma unroll
      for (int mt = 0; mt < 4; ++mt) {      // A[m=lane&15][k8=quad*16+j]
        int r = mt * 16 + l16;
        af[mt] = *(const i32x4*)
            &lA[k * 4096 + r * BK + (((quad + (r >> 1)) & 3) * 16)];
      }
      int sft = k + 1;                       // tap shift as LDS row offset
      #pragma unroll
      for (int nt = 0; nt < 4; ++nt) {      // B^T[t][c]: 16 contiguous c per lane
        int r = wave * 64 + nt * 16 + l16 + sft;
        bf[nt] = *(const i32x4*)
            &lB[r * BK + (((quad + (r >> 1)) & 3) * 16)];
      }
      #pragma unroll
      for (int mt = 0; mt < 4; ++mt)
        #pragma unroll
        for (int nt = 0; nt < 4; ++nt)
          acc[mt][nt] = __builtin_amdgcn_mfma_i32_16x16x64_i8(
              af[mt], bf[nt], acc[mt][nt], 0, 0, 0);
    }
    __syncthreads();
  }
  // epilogue: dequant scale. C/D layout: col=lane&15, row=quad*4+reg
  float sc  = fmaxf(__uint_as_float(*scale_bits), 1e-5f);
  float wsc = fmaxf((float)(*wsum * (1.0 / (double)NW)), 1e-4f);
  float alpha = sc * (1.0f / 127.0f) * wsc;
  #pragma unroll
  for (int mt = 0; mt < 4; ++mt) {
    int o = o0 + mt * 16 + quad * 4;
    #pragma unroll
    for (int nt = 0; nt < 4; ++nt) {
      int t = t0 + wave * 64 + nt * 16 + l16;
      float* po = out + ((size_t)b * O_ + o) * T_ + t;
      #pragma unroll
      for (int r2 = 0; r2 < 4; ++r2)
        po[(size_t)r2 * T_] = (float)acc[mt][nt][r2] * alpha;
    }
  }
}

extern "C" void kernel_launch(void* const* d_in, const int* in_sizes, int n_in,
                              void* d_out, int out_size, void* d_ws, size_t ws_size,
                              hipStream_t stream)
{
  const float* x     = (const float*)d_in[0];
  const float* w     = (const float*)d_in[1];
  const float* gamma = (const float*)d_in[2];
  float* out = (float*)d_out;
  char* ws = (char*)d_ws;
  // ws layout:
  //   [0]       unsigned scale_bits (absmax of normalized x, as float bits)
  //   [16]      double   wsum (sum |w|)
  //   [256]     float    rms[B_*T_]                       (256 KB)
  //   [262400]  int8     wqi[KW][O_][C_]                   (1.84 MB)
  //   [2359552] int8     qa[B_][QT_ROWS][C_]               (33.7 MB)
  unsigned* scale_bits = (unsigned*)ws;
  double*   wsum       = (double*)(ws + 16);
  float*    rms        = (float*)(ws + 256);
  char*     wqi        = (char*)(ws + 262400);
  char*     qa         = (char*)(ws + 2359552);

  hipMemsetAsync(ws, 0, 256, stream);
  k_rms  <<<dim3(B_*T_/256),        256, 0, stream>>>(x, gamma, rms, scale_bits);
  k_wsum <<<dim3(1792),             256, 0, stream>>>(w, wsum, qa);
  k_wq   <<<dim3(O_*C_/256),        256, 0, stream>>>(w, wsum, wqi);
  k_quant<<<dim3(T_/64, C_/64, B_), 256, 0, stream>>>(x, gamma, rms, scale_bits, qa);
  k_conv <<<dim3(T_/NT, O_/MT, B_), 256, 0, stream>>>(wqi, qa, out, scale_bits, wsum);
}